// Round 1
// baseline (623.439 us; speedup 1.0000x reference)
//
#include <hip/hip_runtime.h>
#include <hip/hip_bf16.h>
#include <stdint.h>

#define NN 50000
#define NE 800000
#define NR 16
#define NP (NN * NR)                 // 800000 (rel,dst) bins
#define NB1 ((NP + 255) / 256)       // 3125
#define NTILES ((NN + 127) / 128)    // 391

typedef unsigned short u16;
typedef unsigned int u32;

typedef __bf16 bf16x8 __attribute__((ext_vector_type(8)));
typedef __bf16 bf16x2 __attribute__((ext_vector_type(2)));
typedef float f32x4 __attribute__((ext_vector_type(4)));

__device__ __forceinline__ u16 f2bf(float f) {
  u32 u = __float_as_uint(f);
  u = u + 0x7FFFu + ((u >> 16) & 1u);
  return (u16)(u >> 16);
}

__device__ __forceinline__ u32 pk2bf(float x, float y) {
#if __has_builtin(__builtin_amdgcn_cvt_pk_bf16_f32)
  bf16x2 r = __builtin_amdgcn_cvt_pk_bf16_f32(x, y);
  union { bf16x2 v; u32 u; } c;
  c.v = r;
  return c.u;
#else
  return (u32)f2bf(x) | ((u32)f2bf(y) << 16);
#endif
}

__device__ __forceinline__ float bflo(u32 w) { return __uint_as_float(w << 16); }
__device__ __forceinline__ float bfhi(u32 w) { return __uint_as_float(w & 0xFFFF0000u); }

// ---------------- edge sort by (rel, dst) — counting sort over NP bins ----------------
// Key change vs previous version: bin = rel*NN + dst (was dst*NR + rel), so that for a
// fixed rel the edges of any contiguous node range are contiguous -> fused kernel can
// aggregate one rel for a 128-node tile from one contiguous esd range.
__global__ void hist_kernel(const int* __restrict__ dst, const int* __restrict__ rel,
                            int* __restrict__ counts) {
  int e = blockIdx.x * 256 + threadIdx.x;
  if (e < NE) atomicAdd(&counts[rel[e] * NN + dst[e]], 1);
}

__global__ void scan_partial(const int* __restrict__ counts, int* __restrict__ bsum) {
  __shared__ int buf[256];
  int t = threadIdx.x;
  int i = blockIdx.x * 256 + t;
  int v = (i < NP) ? counts[i] : 0;
  buf[t] = v;
  __syncthreads();
  for (int off = 1; off < 256; off <<= 1) {
    int x = buf[t];
    int y = (t >= off) ? buf[t - off] : 0;
    __syncthreads();
    buf[t] = x + y;
    __syncthreads();
  }
  if (t == 255) bsum[blockIdx.x] = buf[255];
}

// single block, 1024 threads, 4-serial each: scans NB1 (<=4096) block sums
__global__ void scan_mid(const int* __restrict__ bsum, int* __restrict__ boff,
                         int* __restrict__ total_out) {
  __shared__ int buf[1024];
  int t = threadIdx.x;
  int v[4];
  int sum = 0;
#pragma unroll
  for (int i = 0; i < 4; ++i) {
    int idx = t * 4 + i;
    v[i] = (idx < NB1) ? bsum[idx] : 0;
    sum += v[i];
  }
  buf[t] = sum;
  __syncthreads();
  for (int off = 1; off < 1024; off <<= 1) {
    int x = buf[t];
    int y = (t >= off) ? buf[t - off] : 0;
    __syncthreads();
    buf[t] = x + y;
    __syncthreads();
  }
  int excl = buf[t] - sum;
#pragma unroll
  for (int i = 0; i < 4; ++i) {
    int idx = t * 4 + i;
    if (idx < NB1) { boff[idx] = excl; excl += v[i]; }
  }
  if (t == 1023) *total_out = buf[1023];
}

__global__ void scan_final(const int* __restrict__ counts, const int* __restrict__ boff,
                           int* __restrict__ starts, int* __restrict__ cursor) {
  __shared__ int buf[256];
  int t = threadIdx.x;
  int i = blockIdx.x * 256 + t;
  int v = (i < NP) ? counts[i] : 0;
  buf[t] = v;
  __syncthreads();
  for (int off = 1; off < 256; off <<= 1) {
    int x = buf[t];
    int y = (t >= off) ? buf[t - off] : 0;
    __syncthreads();
    buf[t] = x + y;
    __syncthreads();
  }
  int s = boff[blockIdx.x] + buf[t] - v;
  if (i < NP) {
    starts[i] = s;
    cursor[i] = s;
  }
}

// esd[pos] = { dst<<16 | src, norm_bits }   (both node ids < 50000 < 65536)
__global__ void scatter_kernel(const int* __restrict__ src, const int* __restrict__ dst,
                               const int* __restrict__ rel, const float* __restrict__ norm,
                               int* __restrict__ cursor, uint2* __restrict__ esd) {
  int e = blockIdx.x * 256 + threadIdx.x;
  if (e < NE) {
    int d = dst[e];
    int pos = atomicAdd(&cursor[rel[e] * NN + d], 1);
    esd[pos] = make_uint2(((u32)d << 16) | (u32)src[e], __float_as_uint(norm[e]));
  }
}

// ---------------- weight convert: Wt[mat][d][k] = bf16(W[mat][k][d]) ----------------
// mats 0..15 = w0 rels, 16 = lw0, 17..32 = w1 rels, 33 = lw1
__global__ void convert_wt(const float* __restrict__ w0, const float* __restrict__ lw0,
                           const float* __restrict__ w1, const float* __restrict__ lw1,
                           u16* __restrict__ Wt) {
  int m = blockIdx.y;
  int idx = blockIdx.x * 256 + threadIdx.x; // 0..16383
  int d = idx >> 7, k = idx & 127;
  const float* s;
  if (m < 16) s = w0 + (size_t)m * 16384;
  else if (m == 16) s = lw0;
  else if (m < 33) s = w1 + (size_t)(m - 17) * 16384;
  else s = lw1;
  Wt[(size_t)m * 16384 + idx] = f2bf(s[k * 128 + d]);
}

// ---------------- h f32 -> bf16 (layer 0 input only) ----------------
__global__ void hconv_kernel(const float* __restrict__ h, u16* __restrict__ hbf) {
  int i = blockIdx.x * 256 + threadIdx.x; // float4 index
  float4 v = ((const float4*)h)[i];
  ushort4 u;
  u.x = f2bf(v.x); u.y = f2bf(v.y); u.z = f2bf(v.z); u.w = f2bf(v.w);
  ((ushort4*)hbf)[i] = u;
}

// ---------------- gate table: gates[r][n] = sigmoid(hbf[n] . gw[r]) ----------------
__global__ void gates_kernel(const u16* __restrict__ hbf, const float* __restrict__ gw,
                             float* __restrict__ gates) {
  __shared__ float hs[16 * 132];
  __shared__ float gws[16 * 132];
  int t = threadIdx.x;
  int n0 = blockIdx.x * 16;
#pragma unroll
  for (int i = 0; i < 2; ++i) {
    int f = t + 256 * i;            // 0..511
    int row = f >> 5, c4 = (f & 31) * 4;
    ushort4 u = *(const ushort4*)&hbf[(size_t)(n0 + row) * 128 + c4];
    hs[row * 132 + c4 + 0] = __uint_as_float((u32)u.x << 16);
    hs[row * 132 + c4 + 1] = __uint_as_float((u32)u.y << 16);
    hs[row * 132 + c4 + 2] = __uint_as_float((u32)u.z << 16);
    hs[row * 132 + c4 + 3] = __uint_as_float((u32)u.w << 16);
    *(float4*)&gws[row * 132 + c4] = *(const float4*)&gw[row * 128 + c4];
  }
  __syncthreads();
  int nl = t >> 4, r = t & 15;
  float s = 0.f;
#pragma unroll 8
  for (int k = 0; k < 128; ++k) s += hs[nl * 132 + k] * gws[r * 132 + k];
  gates[r * NN + n0 + nl] = 1.f / (1.f + __expf(-s));
}

// ---------------- FUSED aggregate + GEMM ----------------
// One workgroup (4 waves) owns a 128-node output tile. For each of the 16 relations:
//   phase A: each wave aggregates its 32-node sub-range for this rel directly into the
//            LDS As tile (batch-8 esd loads + hbf gathers, wave-uniform flush-walk over
//            dst — edges are sorted by (rel,dst) so per-(wave,rel) range is contiguous).
//            W_r fragments are prefetched into 64 VGPRs at phase start (L2-resident,
//            latency hidden under the aggregation).
//   phase B: MFMA accumulate acc += W_r(frag regs) x As(LDS).
// Mat 16 = self-loop: stage hbf rows into As, MFMA with loop_w.
// The 204.8 MB agg intermediate never touches HBM (was 200 MB write + ~205 MB read
// per layer in the previous split aggregate/biggemm version).
// Numerics identical to prior verified kernel: f32 accumulate per bin, one bf16
// round per (rel,node), identical MFMA fragment/epilogue mapping.
template <int LAYER>
__global__ __launch_bounds__(256, 2)
void fused_kernel(const u16* __restrict__ hbf, const uint2* __restrict__ esd,
                  const float* __restrict__ gates, const int* __restrict__ starts,
                  const u16* __restrict__ Wt, const float* __restrict__ bias,
                  u16* __restrict__ hb_out, float* __restrict__ fout) {
  __shared__ u16 As[128 * 136];      // node-rows tile, pad +8 (272B row stride)
  const u32* hbf32 = (const u32*)hbf;
  int t = threadIdx.x;
  int n0 = blockIdx.x * 128;
  int wave = t >> 6, lane = t & 63;
  int wd = (wave & 1) * 64, wn = (wave >> 1) * 64;
  int mrow = lane & 15, quad = lane >> 4;
  int vbase = n0 + wave * 32;        // this wave's aggregation node range

  float4 bv[4];
#pragma unroll
  for (int i = 0; i < 4; ++i) bv[i] = *(const float4*)&bias[wd + i * 16 + quad * 4];

  f32x4 acc[4][4];
#pragma unroll
  for (int i = 0; i < 4; ++i)
#pragma unroll
    for (int j = 0; j < 4; ++j) acc[i][j] = (f32x4){0.f, 0.f, 0.f, 0.f};

  // lane's flush target: word (row*68 + lane) covers d = 2*lane, 2*lane+1
  u32* asp = (u32*)As + (wave * 32) * 68 + lane;

  for (int m = 0; m < 17; ++m) {
    // ---- prefetch W_m fragments into registers (global loads, L2-hot; latency
    //      hidden under the aggregation phase; barrier drains vmcnt before use) ----
    bf16x8 fw[4][4];
    {
      const u16* wmat = Wt + (size_t)m * 16384;
#pragma unroll
      for (int kk = 0; kk < 4; ++kk)
#pragma unroll
        for (int i2 = 0; i2 < 4; ++i2)
          fw[kk][i2] = *(const bf16x8*)&wmat[(wd + i2 * 16 + mrow) * 128 + kk * 32 + quad * 8];
    }

    if (m < 16) {
      // ---- phase A: aggregate rel m for nodes [vbase, vbase+32) into As ----
      float a0 = 0.f, a1 = 0.f;
      int cur = 0;
      int s = 0, e = 0;
      if (vbase < NN) {
        int vend = vbase + 32;
        if (vend > NN) vend = NN;
        s = starts[m * NN + vbase];
        e = starts[m * NN + vend];   // m=15,vend=NN -> starts[NP] sentinel = NE
      }
      int j = s;
      for (; j + 8 <= e; j += 8) {
        uint2 p[8];
#pragma unroll
        for (int i = 0; i < 8; ++i) p[i] = esd[j + i];
        u32 w[8];
        float gt[8];
#pragma unroll
        for (int i = 0; i < 8; ++i) {
          u32 sn = p[i].x & 0xFFFFu;
          w[i] = hbf32[sn * 64u + (u32)lane];          // L2/L3-resident gather
          gt[i] = gates[(u32)m * (u32)NN + sn];
        }
#pragma unroll
        for (int i = 0; i < 8; ++i) {
          int local = (int)(p[i].x >> 16) - vbase;     // wave-uniform
          while (cur < local) {                        // flush-walk over dst nodes
            asp[cur * 68] = pk2bf(a0, a1);
            a0 = 0.f; a1 = 0.f;
            ++cur;
          }
          float coef = gt[i] * __uint_as_float(p[i].y);
          a0 = fmaf(coef, bflo(w[i]), a0);
          a1 = fmaf(coef, bfhi(w[i]), a1);
        }
      }
      for (; j < e; ++j) {
        uint2 p = esd[j];
        u32 sn = p.x & 0xFFFFu;
        int local = (int)(p.x >> 16) - vbase;
        while (cur < local) {
          asp[cur * 68] = pk2bf(a0, a1);
          a0 = 0.f; a1 = 0.f;
          ++cur;
        }
        float coef = gates[(u32)m * (u32)NN + sn] * __uint_as_float(p.y);
        u32 w = hbf32[sn * 64u + (u32)lane];
        a0 = fmaf(coef, bflo(w), a0);
        a1 = fmaf(coef, bfhi(w), a1);
      }
      while (cur < 32) {                               // zero-fill empty trailing bins
        asp[cur * 68] = pk2bf(a0, a1);
        a0 = 0.f; a1 = 0.f;
        ++cur;
      }
    } else {
      // ---- mat 16: self-loop — stage hbf node rows into As ----
#pragma unroll
      for (int i = 0; i < 8; ++i) {
        int u8 = t + 256 * i;
        int row = u8 >> 4, c8 = (u8 & 15) * 8;
        int n = n0 + row;
        int nc = n < NN ? n : NN - 1;                  // clamp; garbage rows never stored
        *(uint4*)&As[row * 136 + c8] = *(const uint4*)&hbf[(size_t)nc * 128 + c8];
      }
    }
    __syncthreads();                                   // As ready (drains fw loads too)

    // ---- phase B: MFMA accumulate ----
#pragma unroll
    for (int kk = 0; kk < 4; ++kk) {
      int k0 = kk * 32 + quad * 8;
      bf16x8 fb[4];
#pragma unroll
      for (int j2 = 0; j2 < 4; ++j2)
        fb[j2] = *(const bf16x8*)&As[(wn + j2 * 16 + mrow) * 136 + k0];
#pragma unroll
      for (int i2 = 0; i2 < 4; ++i2)
#pragma unroll
        for (int j2 = 0; j2 < 4; ++j2)
          acc[i2][j2] = __builtin_amdgcn_mfma_f32_16x16x32_bf16(fw[kk][i2], fb[j2],
                                                                acc[i2][j2], 0, 0, 0);
    }
    __syncthreads();                                   // all waves done reading As
  }

  // epilogue: lane owns node = n0+wn+j*16+mrow, d = wd+i*16+quad*4 .. +3 (contiguous)
#pragma unroll
  for (int j = 0; j < 4; ++j) {
    int n = n0 + wn + j * 16 + mrow;
    if (n < NN) {
#pragma unroll
      for (int i = 0; i < 4; ++i) {
        int d0 = wd + i * 16 + quad * 4;
        float v0 = acc[i][j][0] + bv[i].x;
        float v1 = acc[i][j][1] + bv[i].y;
        float v2 = acc[i][j][2] + bv[i].z;
        float v3 = acc[i][j][3] + bv[i].w;
        if (LAYER == 0) {
          v0 = fmaxf(v0, 0.f); v1 = fmaxf(v1, 0.f);
          v2 = fmaxf(v2, 0.f); v3 = fmaxf(v3, 0.f);
          uint2 st;
          st.x = pk2bf(v0, v1);
          st.y = pk2bf(v2, v3);
          *(uint2*)&hb_out[(size_t)n * 128 + d0] = st;
        } else {
          float4 st = make_float4(v0, v1, v2, v3);
          *(float4*)&fout[(size_t)n * 128 + d0] = st;
        }
      }
    }
  }
}

// ---------------- host ----------------
extern "C" void kernel_launch(void* const* d_in, const int* in_sizes, int n_in,
                              void* d_out, int out_size, void* d_ws, size_t ws_size,
                              hipStream_t stream) {
  const float* h0   = (const float*)d_in[0];
  const float* norm = (const float*)d_in[1];
  const float* w0   = (const float*)d_in[2];
  const float* b0   = (const float*)d_in[3];
  const float* lw0  = (const float*)d_in[4];
  const float* gw0  = (const float*)d_in[5];
  const float* w1   = (const float*)d_in[6];
  const float* b1   = (const float*)d_in[7];
  const float* lw1  = (const float*)d_in[8];
  const float* gw1  = (const float*)d_in[9];
  const int*   src  = (const int*)d_in[10];
  const int*   dst  = (const int*)d_in[11];
  const int*   rel  = (const int*)d_in[12];
  float* out = (float*)d_out;

  char* p = (char*)d_ws;
  auto alloc = [&](size_t bytes) -> void* {
    void* q = (void*)p;
    p += (bytes + 255) & ~(size_t)255;
    return q;
  };
  u16*   Wt     = (u16*)alloc((size_t)34 * 16384 * 2);
  float* gates  = (float*)alloc((size_t)NR * NN * 4);
  u16*   hbf0   = (u16*)alloc((size_t)NN * 128 * 2);
  u16*   hbf1   = (u16*)alloc((size_t)NN * 128 * 2);
  int*   counts = (int*)alloc((size_t)NP * 4);
  int*   cursor = (int*)alloc((size_t)NP * 4);
  int*   starts = (int*)alloc((size_t)(NP + 1) * 4);
  int*   bsum   = (int*)alloc((size_t)NB1 * 4);
  int*   boff   = (int*)alloc((size_t)NB1 * 4);
  uint2* esd    = (uint2*)alloc((size_t)NE * 8);

  // ---- sort edges by (rel, dst) — shared by both layers ----
  hipMemsetAsync(counts, 0, (size_t)NP * 4, stream);
  hist_kernel<<<NE / 256, 256, 0, stream>>>(dst, rel, counts);
  scan_partial<<<NB1, 256, 0, stream>>>(counts, bsum);
  scan_mid<<<1, 1024, 0, stream>>>(bsum, boff, starts + NP);
  scan_final<<<NB1, 256, 0, stream>>>(counts, boff, starts, cursor);
  scatter_kernel<<<NE / 256, 256, 0, stream>>>(src, dst, rel, norm, cursor, esd);
  convert_wt<<<dim3(64, 34), 256, 0, stream>>>(w0, lw0, w1, lw1, Wt);
  hconv_kernel<<<NN * 32 / 256, 256, 0, stream>>>(h0, hbf0);

  // ---- layer 0 (relu, bf16 output) ----
  gates_kernel<<<NN / 16, 256, 0, stream>>>(hbf0, gw0, gates);
  fused_kernel<0><<<NTILES, 256, 0, stream>>>(hbf0, esd, gates, starts, Wt, b0,
                                              hbf1, nullptr);

  // ---- layer 1 (no relu, f32 output) ----
  gates_kernel<<<NN / 16, 256, 0, stream>>>(hbf1, gw1, gates);
  fused_kernel<1><<<NTILES, 256, 0, stream>>>(hbf1, esd, gates, starts,
                                              Wt + (size_t)17 * 16384, b1,
                                              nullptr, out);
}

// Round 2
// 528.754 us; speedup vs baseline: 1.1791x; 1.1791x over previous
//
#include <hip/hip_runtime.h>
#include <hip/hip_bf16.h>
#include <stdint.h>

#define NN 50000
#define NE 800000
#define NR 16
#define NP (NN * NR)                 // 800000 (rel,dst) bins
#define NB1 ((NP + 255) / 256)       // 3125
#define TN 64                        // fused tile: 64 nodes
#define NT64 ((NN + TN - 1) / TN)    // 782 blocks -> ~3 blocks/CU resident

typedef unsigned short u16;
typedef unsigned int u32;

typedef __bf16 bf16x8 __attribute__((ext_vector_type(8)));
typedef __bf16 bf16x2 __attribute__((ext_vector_type(2)));
typedef float f32x4 __attribute__((ext_vector_type(4)));

__device__ __forceinline__ u16 f2bf(float f) {
  u32 u = __float_as_uint(f);
  u = u + 0x7FFFu + ((u >> 16) & 1u);
  return (u16)(u >> 16);
}

__device__ __forceinline__ u32 pk2bf(float x, float y) {
#if __has_builtin(__builtin_amdgcn_cvt_pk_bf16_f32)
  bf16x2 r = __builtin_amdgcn_cvt_pk_bf16_f32(x, y);
  union { bf16x2 v; u32 u; } c;
  c.v = r;
  return c.u;
#else
  return (u32)f2bf(x) | ((u32)f2bf(y) << 16);
#endif
}

__device__ __forceinline__ float bflo(u32 w) { return __uint_as_float(w << 16); }
__device__ __forceinline__ float bfhi(u32 w) { return __uint_as_float(w & 0xFFFF0000u); }

// ---------------- edge sort by (rel, dst) — counting sort over NP bins ----------------
__global__ void hist_kernel(const int* __restrict__ dst, const int* __restrict__ rel,
                            int* __restrict__ counts) {
  int e = blockIdx.x * 256 + threadIdx.x;
  if (e < NE) atomicAdd(&counts[rel[e] * NN + dst[e]], 1);
}

__global__ void scan_partial(const int* __restrict__ counts, int* __restrict__ bsum) {
  __shared__ int buf[256];
  int t = threadIdx.x;
  int i = blockIdx.x * 256 + t;
  int v = (i < NP) ? counts[i] : 0;
  buf[t] = v;
  __syncthreads();
  for (int off = 1; off < 256; off <<= 1) {
    int x = buf[t];
    int y = (t >= off) ? buf[t - off] : 0;
    __syncthreads();
    buf[t] = x + y;
    __syncthreads();
  }
  if (t == 255) bsum[blockIdx.x] = buf[255];
}

// single block, 1024 threads, 4-serial each: scans NB1 (<=4096) block sums
__global__ void scan_mid(const int* __restrict__ bsum, int* __restrict__ boff,
                         int* __restrict__ total_out) {
  __shared__ int buf[1024];
  int t = threadIdx.x;
  int v[4];
  int sum = 0;
#pragma unroll
  for (int i = 0; i < 4; ++i) {
    int idx = t * 4 + i;
    v[i] = (idx < NB1) ? bsum[idx] : 0;
    sum += v[i];
  }
  buf[t] = sum;
  __syncthreads();
  for (int off = 1; off < 1024; off <<= 1) {
    int x = buf[t];
    int y = (t >= off) ? buf[t - off] : 0;
    __syncthreads();
    buf[t] = x + y;
    __syncthreads();
  }
  int excl = buf[t] - sum;
#pragma unroll
  for (int i = 0; i < 4; ++i) {
    int idx = t * 4 + i;
    if (idx < NB1) { boff[idx] = excl; excl += v[i]; }
  }
  if (t == 1023) *total_out = buf[1023];
}

__global__ void scan_final(const int* __restrict__ counts, const int* __restrict__ boff,
                           int* __restrict__ starts, int* __restrict__ cursor) {
  __shared__ int buf[256];
  int t = threadIdx.x;
  int i = blockIdx.x * 256 + t;
  int v = (i < NP) ? counts[i] : 0;
  buf[t] = v;
  __syncthreads();
  for (int off = 1; off < 256; off <<= 1) {
    int x = buf[t];
    int y = (t >= off) ? buf[t - off] : 0;
    __syncthreads();
    buf[t] = x + y;
    __syncthreads();
  }
  int s = boff[blockIdx.x] + buf[t] - v;
  if (i < NP) {
    starts[i] = s;
    cursor[i] = s;
  }
}

// esd[pos] = { dst<<16 | src, norm_bits }   (both node ids < 50000 < 65536)
__global__ void scatter_kernel(const int* __restrict__ src, const int* __restrict__ dst,
                               const int* __restrict__ rel, const float* __restrict__ norm,
                               int* __restrict__ cursor, uint2* __restrict__ esd) {
  int e = blockIdx.x * 256 + threadIdx.x;
  if (e < NE) {
    int d = dst[e];
    int pos = atomicAdd(&cursor[rel[e] * NN + d], 1);
    esd[pos] = make_uint2(((u32)d << 16) | (u32)src[e], __float_as_uint(norm[e]));
  }
}

// ---------------- weight convert: Wt[mat][d][k] = bf16(W[mat][k][d]) ----------------
// mats 0..15 = w0 rels, 16 = lw0, 17..32 = w1 rels, 33 = lw1
__global__ void convert_wt(const float* __restrict__ w0, const float* __restrict__ lw0,
                           const float* __restrict__ w1, const float* __restrict__ lw1,
                           u16* __restrict__ Wt) {
  int m = blockIdx.y;
  int idx = blockIdx.x * 256 + threadIdx.x; // 0..16383
  int d = idx >> 7, k = idx & 127;
  const float* s;
  if (m < 16) s = w0 + (size_t)m * 16384;
  else if (m == 16) s = lw0;
  else if (m < 33) s = w1 + (size_t)(m - 17) * 16384;
  else s = lw1;
  Wt[(size_t)m * 16384 + idx] = f2bf(s[k * 128 + d]);
}

// ---------------- h f32 -> bf16 (layer 0 input only) ----------------
__global__ void hconv_kernel(const float* __restrict__ h, u16* __restrict__ hbf) {
  int i = blockIdx.x * 256 + threadIdx.x; // float4 index
  float4 v = ((const float4*)h)[i];
  ushort4 u;
  u.x = f2bf(v.x); u.y = f2bf(v.y); u.z = f2bf(v.z); u.w = f2bf(v.w);
  ((ushort4*)hbf)[i] = u;
}

// ---------------- gate table: gates[r][n] = sigmoid(hbf[n] . gw[r]) ----------------
__global__ void gates_kernel(const u16* __restrict__ hbf, const float* __restrict__ gw,
                             float* __restrict__ gates) {
  __shared__ float hs[16 * 132];
  __shared__ float gws[16 * 132];
  int t = threadIdx.x;
  int n0 = blockIdx.x * 16;
#pragma unroll
  for (int i = 0; i < 2; ++i) {
    int f = t + 256 * i;            // 0..511
    int row = f >> 5, c4 = (f & 31) * 4;
    ushort4 u = *(const ushort4*)&hbf[(size_t)(n0 + row) * 128 + c4];
    hs[row * 132 + c4 + 0] = __uint_as_float((u32)u.x << 16);
    hs[row * 132 + c4 + 1] = __uint_as_float((u32)u.y << 16);
    hs[row * 132 + c4 + 2] = __uint_as_float((u32)u.z << 16);
    hs[row * 132 + c4 + 3] = __uint_as_float((u32)u.w << 16);
    *(float4*)&gws[row * 132 + c4] = *(const float4*)&gw[row * 128 + c4];
  }
  __syncthreads();
  int nl = t >> 4, r = t & 15;
  float s = 0.f;
#pragma unroll 8
  for (int k = 0; k < 128; ++k) s += hs[nl * 132 + k] * gws[r * 132 + k];
  gates[r * NN + n0 + nl] = 1.f / (1.f + __expf(-s));
}

// ---------------- FUSED aggregate + GEMM, v2 (latency-hiding rework) ----------------
// Round-0 failure: 391 blocks / 6 waves/CU -> gather latency fully exposed (Occ 15%).
// v2: 64-node tiles (782 blocks, ~3 blocks/CU), double-buffered As with ONE barrier
// per rel: iter m = { MFMA(rel m, buf[m&1]) ; load fw(m+1) ; aggregate(rel m+1 ->
// buf[(m+1)&1]) ; barrier }. MFMA + W loads + starts loads all overlap the gathers.
// Per-wave MFMA state halved (wave owns 32d x 64n: fw[4][2], acc[2][4]) so VGPR fits
// <=128 -> 4 waves/SIMD headroom, no spill.
template <int LAYER>
__global__ __launch_bounds__(256, 4)
void fused_kernel(const u16* __restrict__ hbf, const uint2* __restrict__ esd,
                  const float* __restrict__ gates, const int* __restrict__ starts,
                  const u16* __restrict__ Wt, const float* __restrict__ bias,
                  u16* __restrict__ hb_out, float* __restrict__ fout) {
  __shared__ u16 As[2][TN * 136];    // double-buffered node tile, pad +8 (272B stride)
  const u32* hbf32 = (const u32*)hbf;
  int t = threadIdx.x;
  int n0 = blockIdx.x * TN;
  int wave = t >> 6, lane = t & 63;
  int wd = wave * 32;                // wave owns d rows [wd, wd+32)
  int mrow = lane & 15, quad = lane >> 4;
  int vb = n0 + wave * 16;           // wave's aggregation node range [vb, vb+16)
  int ve = vb + 16;
  if (ve > NN) ve = NN;
  bool aggok = vb < NN;

  f32x4 acc[2][4];
#pragma unroll
  for (int i = 0; i < 2; ++i)
#pragma unroll
    for (int j = 0; j < 4; ++j) acc[i][j] = (f32x4){0.f, 0.f, 0.f, 0.f};

  bf16x8 fw[4][2];

#define LOAD_FW(MAT)                                                          \
  {                                                                           \
    const u16* wmat = Wt + (size_t)(MAT) * 16384;                             \
    _Pragma("unroll")                                                         \
    for (int kk = 0; kk < 4; ++kk)                                            \
      _Pragma("unroll")                                                       \
      for (int i2 = 0; i2 < 2; ++i2)                                          \
        fw[kk][i2] = *(const bf16x8*)&wmat[(wd + i2 * 16 + mrow) * 128 +      \
                                           kk * 32 + quad * 8];               \
  }

  // Aggregate rel R's edges for nodes [vb, ve) into buffer B. Edges sorted by
  // (rel,dst) -> contiguous range, dst nondecreasing -> wave-uniform flush walk.
  // f32 accumulate per (node,d-pair), one bf16 round at flush (same numerics as
  // the verified split kernel).
#define DO_AGG(R, B, S, E)                                                    \
  {                                                                           \
    u32* asp = (u32*)(&As[B][0]) + (wave * 16) * 68 + lane;                   \
    const float* gp = gates + (size_t)(R) * NN;                               \
    float a0 = 0.f, a1 = 0.f;                                                 \
    int cur = 0;                                                              \
    int j = (S);                                                              \
    for (; j + 8 <= (E); j += 8) {                                            \
      uint2 p[8];                                                             \
      _Pragma("unroll")                                                       \
      for (int i = 0; i < 8; ++i) p[i] = esd[j + i];                          \
      u32 w[8];                                                               \
      float gt[8];                                                            \
      _Pragma("unroll")                                                       \
      for (int i = 0; i < 8; ++i) {                                           \
        u32 sn = p[i].x & 0xFFFFu;                                            \
        w[i] = hbf32[sn * 64u + (u32)lane];                                   \
        gt[i] = gp[sn];                                                       \
      }                                                                       \
      _Pragma("unroll")                                                       \
      for (int i = 0; i < 8; ++i) {                                           \
        int local = (int)(p[i].x >> 16) - vb;                                 \
        while (cur < local) {                                                 \
          asp[cur * 68] = pk2bf(a0, a1);                                      \
          a0 = 0.f; a1 = 0.f; ++cur;                                          \
        }                                                                     \
        float coef = gt[i] * __uint_as_float(p[i].y);                         \
        a0 = fmaf(coef, bflo(w[i]), a0);                                      \
        a1 = fmaf(coef, bfhi(w[i]), a1);                                      \
      }                                                                       \
    }                                                                         \
    for (; j < (E); ++j) {                                                    \
      uint2 p = esd[j];                                                       \
      u32 sn = p.x & 0xFFFFu;                                                 \
      int local = (int)(p.x >> 16) - vb;                                      \
      while (cur < local) {                                                   \
        asp[cur * 68] = pk2bf(a0, a1);                                        \
        a0 = 0.f; a1 = 0.f; ++cur;                                            \
      }                                                                       \
      float coef = gp[sn] * __uint_as_float(p.y);                             \
      u32 w1_ = hbf32[sn * 64u + (u32)lane];                                  \
      a0 = fmaf(coef, bflo(w1_), a0);                                         \
      a1 = fmaf(coef, bfhi(w1_), a1);                                         \
    }                                                                         \
    while (cur < 16) {                                                        \
      asp[cur * 68] = pk2bf(a0, a1);                                          \
      a0 = 0.f; a1 = 0.f; ++cur;                                              \
    }                                                                         \
  }

#define DO_MFMA(B)                                                            \
  _Pragma("unroll")                                                           \
  for (int kk = 0; kk < 4; ++kk) {                                            \
    int k0 = kk * 32 + quad * 8;                                              \
    bf16x8 fb[4];                                                             \
    _Pragma("unroll")                                                         \
    for (int j2 = 0; j2 < 4; ++j2)                                            \
      fb[j2] = *(const bf16x8*)&As[B][(j2 * 16 + mrow) * 136 + k0];           \
    _Pragma("unroll")                                                         \
    for (int i2 = 0; i2 < 2; ++i2)                                            \
      _Pragma("unroll")                                                       \
      for (int j2 = 0; j2 < 4; ++j2)                                          \
        acc[i2][j2] = __builtin_amdgcn_mfma_f32_16x16x32_bf16(                \
            fw[kk][i2], fb[j2], acc[i2][j2], 0, 0, 0);                        \
  }

  // rolling (s,e) prefetch: current rel's range preloaded one iteration ahead
  int sC = 0, eC = 0, sN = 0, eN = 0;
  if (aggok) { sC = starts[vb]; eC = starts[ve]; }             // rel 0
  LOAD_FW(0);
  if (aggok) { sN = starts[NN + vb]; eN = starts[NN + ve]; }   // rel 1
  DO_AGG(0, 0, sC, eC);
  __syncthreads();

  for (int m = 0; m < 17; ++m) {
    DO_MFMA(m & 1);
    if (m < 16) LOAD_FW(m + 1);     // latency hides under the aggregation below
    if (m < 15) {
      int r = m + 1;
      sC = sN; eC = eN;
      if (aggok && r < 15) {        // prefetch rel r+1's range for next iter
        sN = starts[(r + 1) * NN + vb];
        eN = starts[(r + 1) * NN + ve];
      }
      DO_AGG(r, (m + 1) & 1, sC, eC);
      __syncthreads();
    } else if (m == 15) {
      // mat 16 = self-loop: stage hbf node rows into buf0 (16&1 == 0)
#pragma unroll
      for (int i = 0; i < 4; ++i) {
        int u8 = t + 256 * i;       // 0..1023 uint4 slots = 64 rows x 16
        int row = u8 >> 4, c8 = (u8 & 15) * 8;
        int n = n0 + row;
        int nc = n < NN ? n : NN - 1;   // clamp; garbage rows never stored
        *(uint4*)&As[0][row * 136 + c8] = *(const uint4*)&hbf[(size_t)nc * 128 + c8];
      }
      __syncthreads();
    }
    // m == 16: no barrier needed, fall through to epilogue
  }

  // epilogue: lane owns node n = n0 + j2*16 + mrow, d = wd + i2*16 + quad*4 .. +3
  float4 bvv[2];
#pragma unroll
  for (int i2 = 0; i2 < 2; ++i2)
    bvv[i2] = *(const float4*)&bias[wd + i2 * 16 + quad * 4];
#pragma unroll
  for (int j2 = 0; j2 < 4; ++j2) {
    int n = n0 + j2 * 16 + mrow;
    if (n < NN) {
#pragma unroll
      for (int i2 = 0; i2 < 2; ++i2) {
        int d0 = wd + i2 * 16 + quad * 4;
        float v0 = acc[i2][j2][0] + bvv[i2].x;
        float v1 = acc[i2][j2][1] + bvv[i2].y;
        float v2 = acc[i2][j2][2] + bvv[i2].z;
        float v3 = acc[i2][j2][3] + bvv[i2].w;
        if (LAYER == 0) {
          v0 = fmaxf(v0, 0.f); v1 = fmaxf(v1, 0.f);
          v2 = fmaxf(v2, 0.f); v3 = fmaxf(v3, 0.f);
          uint2 st;
          st.x = pk2bf(v0, v1);
          st.y = pk2bf(v2, v3);
          *(uint2*)&hb_out[(size_t)n * 128 + d0] = st;
        } else {
          float4 st = make_float4(v0, v1, v2, v3);
          *(float4*)&fout[(size_t)n * 128 + d0] = st;
        }
      }
    }
  }
#undef LOAD_FW
#undef DO_AGG
#undef DO_MFMA
}

// ---------------- host ----------------
extern "C" void kernel_launch(void* const* d_in, const int* in_sizes, int n_in,
                              void* d_out, int out_size, void* d_ws, size_t ws_size,
                              hipStream_t stream) {
  const float* h0   = (const float*)d_in[0];
  const float* norm = (const float*)d_in[1];
  const float* w0   = (const float*)d_in[2];
  const float* b0   = (const float*)d_in[3];
  const float* lw0  = (const float*)d_in[4];
  const float* gw0  = (const float*)d_in[5];
  const float* w1   = (const float*)d_in[6];
  const float* b1   = (const float*)d_in[7];
  const float* lw1  = (const float*)d_in[8];
  const float* gw1  = (const float*)d_in[9];
  const int*   src  = (const int*)d_in[10];
  const int*   dst  = (const int*)d_in[11];
  const int*   rel  = (const int*)d_in[12];
  float* out = (float*)d_out;

  char* p = (char*)d_ws;
  auto alloc = [&](size_t bytes) -> void* {
    void* q = (void*)p;
    p += (bytes + 255) & ~(size_t)255;
    return q;
  };
  u16*   Wt     = (u16*)alloc((size_t)34 * 16384 * 2);
  float* gates  = (float*)alloc((size_t)NR * NN * 4);
  u16*   hbf0   = (u16*)alloc((size_t)NN * 128 * 2);
  u16*   hbf1   = (u16*)alloc((size_t)NN * 128 * 2);
  int*   counts = (int*)alloc((size_t)NP * 4);
  int*   cursor = (int*)alloc((size_t)NP * 4);
  int*   starts = (int*)alloc((size_t)(NP + 1) * 4);
  int*   bsum   = (int*)alloc((size_t)NB1 * 4);
  int*   boff   = (int*)alloc((size_t)NB1 * 4);
  uint2* esd    = (uint2*)alloc((size_t)NE * 8);

  // ---- sort edges by (rel, dst) — shared by both layers ----
  hipMemsetAsync(counts, 0, (size_t)NP * 4, stream);
  hist_kernel<<<NE / 256, 256, 0, stream>>>(dst, rel, counts);
  scan_partial<<<NB1, 256, 0, stream>>>(counts, bsum);
  scan_mid<<<1, 1024, 0, stream>>>(bsum, boff, starts + NP);
  scan_final<<<NB1, 256, 0, stream>>>(counts, boff, starts, cursor);
  scatter_kernel<<<NE / 256, 256, 0, stream>>>(src, dst, rel, norm, cursor, esd);
  convert_wt<<<dim3(64, 34), 256, 0, stream>>>(w0, lw0, w1, lw1, Wt);
  hconv_kernel<<<NN * 32 / 256, 256, 0, stream>>>(h0, hbf0);

  // ---- layer 0 (relu, bf16 output) ----
  gates_kernel<<<NN / 16, 256, 0, stream>>>(hbf0, gw0, gates);
  fused_kernel<0><<<NT64, 256, 0, stream>>>(hbf0, esd, gates, starts, Wt, b0,
                                            hbf1, nullptr);

  // ---- layer 1 (no relu, f32 output) ----
  gates_kernel<<<NN / 16, 256, 0, stream>>>(hbf1, gw1, gates);
  fused_kernel<1><<<NT64, 256, 0, stream>>>(hbf1, esd, gates, starts,
                                            Wt + (size_t)17 * 16384, b1,
                                            nullptr, out);
}